// Round 1
// 615.895 us; speedup vs baseline: 1.0521x; 1.0521x over previous
//
#include <hip/hip_runtime.h>

typedef unsigned short u16t;
typedef __bf16 bf16x8 __attribute__((ext_vector_type(8)));
typedef float f32x4 __attribute__((ext_vector_type(4)));

#define NB 4
#define NS 2048
#define ND 1024
#define NH 16
#define NDK 64
#define SCALE_ 0.125f
#define NEGINF -1.0e9f

// padded LDS row strides (elements). 64-wide tiles: 72 (=144B, 9 granules,
// coprime with 8 -> consecutive rows rotate bank-granule slots -> conflict-free
// ds_read_b128). 32-wide gemm tiles: 40 (=80B, 5 granules, coprime with 8).
#define LKV 72
#define LAB 40

// load 8 contiguous elements as bf16x8 (fp32 source converts RNE via (__bf16))
__device__ __forceinline__ bf16x8 load8_cvt(const float* p) {
  const f32x4 a = *(const f32x4*)p;
  const f32x4 b = *(const f32x4*)(p + 4);
  bf16x8 r;
  r[0] = (__bf16)a[0]; r[1] = (__bf16)a[1]; r[2] = (__bf16)a[2]; r[3] = (__bf16)a[3];
  r[4] = (__bf16)b[0]; r[5] = (__bf16)b[1]; r[6] = (__bf16)b[2]; r[7] = (__bf16)b[3];
  return r;
}
__device__ __forceinline__ bf16x8 load8_cvt(const u16t* p) {
  return *(const bf16x8*)p;
}
__device__ __forceinline__ u16t f2bf(float f) {
  unsigned u = __builtin_bit_cast(unsigned, f);
  u += 0x7fffu + ((u >> 16) & 1u);   // RNE
  return (u16t)(u >> 16);
}

// ---------------------------------------------------------------------------
// NT GEMM: C[M,N] = A[M,K] * B[N,K]^T ; M=8192, N=K=1024, bf16 MFMA, fp32 acc.
// A dtype: fp32 (raw inputs) or bf16/u16t (ctx scratch). B is always fp32 W.
// MODE 0: C fp32 row-major [M,N] + bias[col]   (output projection -> d_out)
// MODE 1: C bf16 scatter to [B,H,S,dk]         (Q/K projections -> ws)
// MODE 2: C bf16 scatter to [B,H,dk,S]         (V projection, transposed -> ws)
// 128x128 tile, BK=32, 256 threads (4 waves, 2x2 of 64x64 per-wave tiles).
// ---------------------------------------------------------------------------
template<typename TA, int MODE>
__global__ __launch_bounds__(256, 2)
void gemm_nt(const TA* __restrict__ A, const float* __restrict__ Bm,
             void* __restrict__ Cv, const float* __restrict__ bias)
{
  const int K = 1024;
  __shared__ __attribute__((aligned(16))) u16t At[128 * LAB];
  __shared__ __attribute__((aligned(16))) u16t Bt[128 * LAB];

  const int tid  = threadIdx.x;
  const int w    = tid >> 6;
  const int lane = tid & 63;
  const int quad = lane >> 4;
  const int l16  = lane & 15;
  const int wm   = w >> 1, wn = w & 1;
  const int m0   = blockIdx.x * 128;
  const int n0   = blockIdx.y * 128;

  const f32x4 fz = {0.f, 0.f, 0.f, 0.f};
  f32x4 acc[4][4];
#pragma unroll
  for (int i = 0; i < 4; i++)
#pragma unroll
    for (int j = 0; j < 4; j++) acc[i][j] = fz;

  // staging chunk map: chunk c (0..511) -> row c>>2 (0..127), colgrp (c&3)*8
  const int r0 = tid >> 2, cg = (tid & 3) * 8;
  const int r1 = r0 + 64;

  for (int k0 = 0; k0 < K; k0 += 32) {
    bf16x8 va0 = load8_cvt(A  + (long)(m0 + r0) * K + k0 + cg);
    bf16x8 va1 = load8_cvt(A  + (long)(m0 + r1) * K + k0 + cg);
    bf16x8 vb0 = load8_cvt(Bm + (long)(n0 + r0) * K + k0 + cg);
    bf16x8 vb1 = load8_cvt(Bm + (long)(n0 + r1) * K + k0 + cg);
    __syncthreads();
    *(bf16x8*)&At[r0 * LAB + cg] = va0;
    *(bf16x8*)&At[r1 * LAB + cg] = va1;
    *(bf16x8*)&Bt[r0 * LAB + cg] = vb0;
    *(bf16x8*)&Bt[r1 * LAB + cg] = vb1;
    __syncthreads();

    bf16x8 af[4], bfv[4];
#pragma unroll
    for (int i = 0; i < 4; i++)
      af[i] = *(const bf16x8*)&At[(wm * 64 + i * 16 + l16) * LAB + quad * 8];
#pragma unroll
    for (int j = 0; j < 4; j++)
      bfv[j] = *(const bf16x8*)&Bt[(wn * 64 + j * 16 + l16) * LAB + quad * 8];
#pragma unroll
    for (int i = 0; i < 4; i++)
#pragma unroll
      for (int j = 0; j < 4; j++)
        acc[i][j] = __builtin_amdgcn_mfma_f32_16x16x32_bf16(af[i], bfv[j], acc[i][j], 0, 0, 0);
  }

#pragma unroll
  for (int i = 0; i < 4; i++) {
    const int rbase = m0 + wm * 64 + i * 16 + quad * 4;
#pragma unroll
    for (int j = 0; j < 4; j++) {
      const int col = n0 + wn * 64 + j * 16 + l16;
      float bv = 0.f;
      if (MODE == 0) bv = bias[col];
#pragma unroll
      for (int r = 0; r < 4; r++) {
        const int row = rbase + r;
        float v = acc[i][j][r];
        if (MODE == 0) {
          ((float*)Cv)[(long)row * ND + col] = v + bv;
        } else if (MODE == 1) {
          int b = row >> 11, s = row & 2047, h = col >> 6, d = col & 63;
          ((u16t*)Cv)[(((long)(b * NH + h)) * NS + s) * NDK + d] = f2bf(v);
        } else {
          int b = row >> 11, s = row & 2047, h = col >> 6, d = col & 63;
          ((u16t*)Cv)[(((long)(b * NH + h)) * NDK + d) * NS + s] = f2bf(v);
        }
      }
    }
  }
}

// ---------------------------------------------------------------------------
// Flash attention pass: per (b,h, 128-row q tile). Each of the 4 waves owns 32
// q rows. Online softmax over 64-key blocks. Writes context (bf16, [B,S,D]
// layout) and final row max m / row sum l (fp32) for the probs_mean pass.
// LDS tiles padded to stride LKV=72 elem (144B) -> conflict-free b128 reads.
// ---------------------------------------------------------------------------
__global__ __launch_bounds__(256, 3)
void flash_ctx(const u16t* __restrict__ Qw, const u16t* __restrict__ Kw,
               const u16t* __restrict__ VTw, const int* __restrict__ mask,
               u16t* __restrict__ ctx, float* __restrict__ mo, float* __restrict__ lo)
{
  __shared__ __attribute__((aligned(16))) u16t Kt[64 * LKV];
  __shared__ __attribute__((aligned(16))) u16t Vt[64 * LKV];
  __shared__ __attribute__((aligned(16))) u16t Pt[4 * 32 * LKV];
  __shared__ float biasl[NS];

  const int tid  = threadIdx.x;
  const int w    = tid >> 6;
  const int lane = tid & 63;
  const int quad = lane >> 4;
  const int l16  = lane & 15;
  const int bh   = blockIdx.y;        // b*16 + h
  const int b    = bh >> 4;
  const int h    = bh & 15;
  const int qw   = blockIdx.x * 128 + w * 32;

  for (int i = tid; i < NS; i += 256)
    biasl[i] = mask[b * NS + i] ? 0.f : NEGINF;

  // preload this wave's Q fragments (32 rows x 64 d) into registers
  bf16x8 qf[2][2];
#pragma unroll
  for (int g = 0; g < 2; g++)
#pragma unroll
    for (int kk = 0; kk < 2; kk++)
      qf[g][kk] = *(const bf16x8*)(Qw + ((long)bh * NS + qw + g * 16 + l16) * NDK + kk * 32 + quad * 8);

  const f32x4 fz = {0.f, 0.f, 0.f, 0.f};
  const f32x4 fm = {NEGINF, NEGINF, NEGINF, NEGINF};
  f32x4 cacc[2][4];
#pragma unroll
  for (int g = 0; g < 2; g++)
#pragma unroll
    for (int d = 0; d < 4; d++) cacc[g][d] = fz;
  f32x4 mrun[2] = {fm, fm};
  f32x4 lrun[2] = {fz, fz};

  // staging chunk map: chunk c (0..511) -> row c>>3 (0..63), colgrp (c&7)*8
  const int kr0 = tid >> 3, kc0 = (tid & 7) * 8;
  const int kr1 = kr0 + 32;

  for (int kb = 0; kb < NS; kb += 64) {
    bf16x8 k0v = *(const bf16x8*)(Kw  + ((long)bh * NS + kb + kr0) * NDK + kc0);
    bf16x8 k1v = *(const bf16x8*)(Kw  + ((long)bh * NS + kb + kr1) * NDK + kc0);
    bf16x8 v0v = *(const bf16x8*)(VTw + ((long)bh * NDK + kr0) * NS + kb + kc0);
    bf16x8 v1v = *(const bf16x8*)(VTw + ((long)bh * NDK + kr1) * NS + kb + kc0);
    __syncthreads();
    *(bf16x8*)&Kt[kr0 * LKV + kc0] = k0v;
    *(bf16x8*)&Kt[kr1 * LKV + kc0] = k1v;
    *(bf16x8*)&Vt[kr0 * LKV + kc0] = v0v;
    *(bf16x8*)&Vt[kr1 * LKV + kc0] = v1v;
    __syncthreads();

    // S = Q K^T (rows: q, cols: key)
    f32x4 s[2][4];
#pragma unroll
    for (int g = 0; g < 2; g++)
#pragma unroll
      for (int c = 0; c < 4; c++) {
        f32x4 a = fz;
#pragma unroll
        for (int kk = 0; kk < 2; kk++) {
          bf16x8 kf = *(const bf16x8*)&Kt[(c * 16 + l16) * LKV + kk * 32 + quad * 8];
          a = __builtin_amdgcn_mfma_f32_16x16x32_bf16(qf[g][kk], kf, a, 0, 0, 0);
        }
        s[g][c] = a;
      }

    float bias_c[4];
#pragma unroll
    for (int c = 0; c < 4; c++) bias_c[c] = biasl[kb + c * 16 + l16];

#pragma unroll
    for (int g = 0; g < 2; g++) {
#pragma unroll
      for (int c = 0; c < 4; c++)
#pragma unroll
        for (int r = 0; r < 4; r++)
          s[g][c][r] = s[g][c][r] * SCALE_ + bias_c[c];

      // row max across 4 col-frags then across the 16 col lanes
      f32x4 mx = s[g][0];
#pragma unroll
      for (int c = 1; c < 4; c++)
#pragma unroll
        for (int r = 0; r < 4; r++) mx[r] = fmaxf(mx[r], s[g][c][r]);
#pragma unroll
      for (int off = 1; off < 16; off <<= 1)
#pragma unroll
        for (int r = 0; r < 4; r++) mx[r] = fmaxf(mx[r], __shfl_xor(mx[r], off, 64));

      f32x4 alpha;
#pragma unroll
      for (int r = 0; r < 4; r++) {
        float mnew = fmaxf(mrun[g][r], mx[r]);
        alpha[r] = __expf(mrun[g][r] - mnew);
        mrun[g][r] = mnew;
      }
#pragma unroll
      for (int c = 0; c < 4; c++)
#pragma unroll
        for (int r = 0; r < 4; r++) s[g][c][r] = __expf(s[g][c][r] - mrun[g][r]);

      f32x4 sm = fz;
#pragma unroll
      for (int c = 0; c < 4; c++)
#pragma unroll
        for (int r = 0; r < 4; r++) sm[r] += s[g][c][r];
#pragma unroll
      for (int off = 1; off < 16; off <<= 1)
#pragma unroll
        for (int r = 0; r < 4; r++) sm[r] += __shfl_xor(sm[r], off, 64);
#pragma unroll
      for (int r = 0; r < 4; r++) lrun[g][r] = lrun[g][r] * alpha[r] + sm[r];
#pragma unroll
      for (int d = 0; d < 4; d++)
#pragma unroll
        for (int r = 0; r < 4; r++) cacc[g][d][r] *= alpha[r];

      // P -> LDS (A-operand layout: [q][key] row-major, contiguous keys)
#pragma unroll
      for (int c = 0; c < 4; c++)
#pragma unroll
        for (int r = 0; r < 4; r++)
          Pt[w * 32 * LKV + (g * 16 + quad * 4 + r) * LKV + c * 16 + l16] = f2bf(s[g][c][r]);
    }

    // context += P * V  (Pt region is per-wave; same-wave DS ops are in order)
#pragma unroll
    for (int g = 0; g < 2; g++)
#pragma unroll
      for (int d = 0; d < 4; d++)
#pragma unroll
        for (int kk = 0; kk < 2; kk++) {
          bf16x8 pf = *(const bf16x8*)&Pt[w * 32 * LKV + (g * 16 + l16) * LKV + kk * 32 + quad * 8];
          bf16x8 vf = *(const bf16x8*)&Vt[(d * 16 + l16) * LKV + kk * 32 + quad * 8];
          cacc[g][d] = __builtin_amdgcn_mfma_f32_16x16x32_bf16(pf, vf, cacc[g][d], 0, 0, 0);
        }
  }

  // epilogue: normalize, write context and (m,l)
#pragma unroll
  for (int g = 0; g < 2; g++) {
    f32x4 rinv;
#pragma unroll
    for (int r = 0; r < 4; r++) rinv[r] = 1.f / lrun[g][r];
#pragma unroll
    for (int d = 0; d < 4; d++)
#pragma unroll
      for (int r = 0; r < 4; r++) {
        int qg = qw + g * 16 + quad * 4 + r;
        int e  = h * NDK + d * 16 + l16;
        ctx[((long)(b * NS + qg)) * ND + e] = f2bf(cacc[g][d][r] * rinv[r]);
      }
    if (l16 == 0) {
#pragma unroll
      for (int r = 0; r < 4; r++) {
        int qg = qw + g * 16 + quad * 4 + r;
        mo[(long)bh * NS + qg] = mrun[g][r];
        lo[(long)bh * NS + qg] = lrun[g][r];
      }
    }
  }
}

// ---------------------------------------------------------------------------
// probs_mean: per (b, 128x128 score tile), loop all 16 heads recomputing
// S = Q K^T, p = exp(s*scale + maskbias - m)/l, accumulate mean, write fp32.
// ---------------------------------------------------------------------------
__global__ __launch_bounds__(256, 2)
void probs_mean(const u16t* __restrict__ Qw, const u16t* __restrict__ Kw,
                const int* __restrict__ mask, const float* __restrict__ mo,
                const float* __restrict__ lo, float* __restrict__ outp)
{
  __shared__ __attribute__((aligned(16))) u16t Qt[128 * LKV];
  __shared__ __attribute__((aligned(16))) u16t Kt2[128 * LKV];
  __shared__ float ml[NH * 128];
  __shared__ float li[NH * 128];
  __shared__ float biasl[128];

  const int tid  = threadIdx.x;
  const int w    = tid >> 6;
  const int lane = tid & 63;
  const int quad = lane >> 4;
  const int l16  = lane & 15;
  const int wm   = w >> 1, wn = w & 1;
  const int b  = blockIdx.z;
  const int q0 = blockIdx.y * 128;
  const int k0 = blockIdx.x * 128;

  for (int i = tid; i < NH * 128; i += 256) {
    int hh = i >> 7, r = i & 127;
    ml[i] = mo[((long)(b * NH + hh)) * NS + q0 + r];
    li[i] = 1.f / lo[((long)(b * NH + hh)) * NS + q0 + r];
  }
  for (int i = tid; i < 128; i += 256)
    biasl[i] = mask[b * NS + k0 + i] ? 0.f : NEGINF;

  const f32x4 fz = {0.f, 0.f, 0.f, 0.f};
  f32x4 acc[4][4];
#pragma unroll
  for (int i = 0; i < 4; i++)
#pragma unroll
    for (int j = 0; j < 4; j++) acc[i][j] = fz;

  for (int hh = 0; hh < NH; hh++) {
    // stage Q tile [128x64] and K tile [128x64]: 1024 chunks each, 4/thread
    bf16x8 qv[4], kv[4];
#pragma unroll
    for (int rr = 0; rr < 4; rr++) {
      int idx = rr * 256 + tid;
      int row = idx >> 3, off = (idx & 7) * 8;
      qv[rr] = *(const bf16x8*)(Qw + ((long)(b * NH + hh) * NS + q0 + row) * NDK + off);
      kv[rr] = *(const bf16x8*)(Kw + ((long)(b * NH + hh) * NS + k0 + row) * NDK + off);
    }
    __syncthreads();
#pragma unroll
    for (int rr = 0; rr < 4; rr++) {
      int idx = rr * 256 + tid;
      int row = idx >> 3, off = (idx & 7) * 8;
      *(bf16x8*)&Qt[row * LKV + off]  = qv[rr];
      *(bf16x8*)&Kt2[row * LKV + off] = kv[rr];
    }
    __syncthreads();

    bf16x8 af[4][2], bfv[4][2];
#pragma unroll
    for (int i = 0; i < 4; i++)
#pragma unroll
      for (int kk = 0; kk < 2; kk++) {
        af[i][kk]  = *(const bf16x8*)&Qt[(wm * 64 + i * 16 + l16) * LKV + kk * 32 + quad * 8];
        bfv[i][kk] = *(const bf16x8*)&Kt2[(wn * 64 + i * 16 + l16) * LKV + kk * 32 + quad * 8];
      }
#pragma unroll
    for (int i = 0; i < 4; i++)
#pragma unroll
      for (int j = 0; j < 4; j++) {
        f32x4 s = fz;
#pragma unroll
        for (int kk = 0; kk < 2; kk++)
          s = __builtin_amdgcn_mfma_f32_16x16x32_bf16(af[i][kk], bfv[j][kk], s, 0, 0, 0);
        const float bias_c = biasl[wn * 64 + j * 16 + l16];
#pragma unroll
        for (int r = 0; r < 4; r++) {
          int rowb = wm * 64 + i * 16 + quad * 4 + r;
          float p = __expf(s[r] * SCALE_ + bias_c - ml[hh * 128 + rowb]) * li[hh * 128 + rowb];
          acc[i][j][r] += p;
        }
      }
  }

#pragma unroll
  for (int i = 0; i < 4; i++)
#pragma unroll
    for (int j = 0; j < 4; j++)
#pragma unroll
      for (int r = 0; r < 4; r++) {
        int row = q0 + wm * 64 + i * 16 + quad * 4 + r;
        int col = k0 + wn * 64 + j * 16 + l16;
        outp[((long)(b * NS + row)) * NS + col] = acc[i][j][r] * (1.f / 16.f);
      }
}

// ---------------------------------------------------------------------------
extern "C" void kernel_launch(void* const* d_in, const int* in_sizes, int n_in,
                              void* d_out, int out_size, void* d_ws, size_t ws_size,
                              hipStream_t stream)
{
  (void)in_sizes; (void)n_in; (void)out_size; (void)ws_size;
  const float* query = (const float*)d_in[0];
  const float* keyt  = (const float*)d_in[1];
  const float* value = (const float*)d_in[2];
  const int*   mask  = (const int*)d_in[3];
  const float* Wq = (const float*)d_in[4];
  const float* Wk = (const float*)d_in[5];
  const float* Wv = (const float*)d_in[6];
  const float* Wo = (const float*)d_in[7];
  const float* bo = (const float*)d_in[8];

  float* out  = (float*)d_out;                     // [B,S,D] fp32
  float* outp = out + (long)NB * NS * ND;          // [B,S,S] fp32

  u16t* q_ws  = (u16t*)d_ws;                       // [B,H,S,dk] bf16
  u16t* k_ws  = q_ws + (long)NB * NH * NS * NDK;   // [B,H,S,dk] bf16
  u16t* vt_ws = k_ws + (long)NB * NH * NS * NDK;   // [B,H,dk,S] bf16
  float* m_ws = (float*)(vt_ws + (long)NB * NH * NS * NDK);
  float* l_ws = m_ws + (long)NB * NH * NS;
  // ctx scratch (bf16) lives in the outp region of d_out; it is fully
  // consumed by the output GEMM before probs_mean overwrites the region.
  u16t* ctx_ws = (u16t*)outp;

  dim3 blk(256);
  gemm_nt<float, 1><<<dim3(64, 8), blk, 0, stream>>>(query, Wq, q_ws, nullptr);
  gemm_nt<float, 1><<<dim3(64, 8), blk, 0, stream>>>(keyt,  Wk, k_ws, nullptr);
  gemm_nt<float, 2><<<dim3(64, 8), blk, 0, stream>>>(value, Wv, vt_ws, nullptr);
  flash_ctx<<<dim3(NS / 128, NB * NH), blk, 0, stream>>>(q_ws, k_ws, vt_ws, mask,
                                                         ctx_ws, m_ws, l_ws);
  gemm_nt<u16t, 0><<<dim3(64, 8), blk, 0, stream>>>(ctx_ws, Wo, out, bo);
  probs_mean<<<dim3(NS / 128, NS / 128, NB), blk, 0, stream>>>(q_ws, k_ws, mask,
                                                               m_ws, l_ws, outp);
}